// Round 2
// baseline (465.786 us; speedup 1.0000x reference)
//
#include <hip/hip_runtime.h>
#include <math.h>

namespace {
constexpr int kB = 2, kH = 16, kS = 2048, kD = 64, kC = 64;
constexpr int kNC = kS / kC;          // 32 chunks
constexpr float kScale = 0.125f;      // 1/sqrt(64)
}

// ---------------------------------------------------------------------------
// Pass 1: per-chunk partial state A_c[d][e] = sum_j gamma^(C-1-j) k[j][d] v[j][e]
// grid = B*H*NC blocks, 256 threads
// ---------------------------------------------------------------------------
__global__ __launch_bounds__(256) void ret_partial(const float* __restrict__ K,
                                                   const float* __restrict__ V,
                                                   float* __restrict__ A) {
  const int idx = blockIdx.x;               // (b*H + h)*NC + c
  const int h = (idx / kNC) % kH;
  const int t = threadIdx.x;

  __shared__ float ks[kC * kD];
  __shared__ float vs[kC * kD];
  __shared__ float pt[kC + 1];

  const size_t gbase = (size_t)idx * (kC * kD);
  {
    const float4* gk = (const float4*)(K + gbase);
    const float4* gv = (const float4*)(V + gbase);
#pragma unroll
    for (int n = 0; n < 4; ++n) {
      ((float4*)ks)[t + 256 * n] = gk[t + 256 * n];
      ((float4*)vs)[t + 256 * n] = gv[t + 256 * n];
    }
  }
  const float log2g = log2f(1.0f - exp2f(-5.0f - (float)h));
  if (t <= kC) pt[t] = exp2f((float)t * log2g);
  __syncthreads();

  const int d = t >> 2;
  const int e0 = (t & 3) * 16;
  float acc[16];
#pragma unroll
  for (int m = 0; m < 16; ++m) acc[m] = 0.0f;

  for (int j = 0; j < kC; ++j) {
    const float wk = pt[kC - 1 - j] * ks[j * kD + d];   // d stride-1 across lanes: conflict-free
    const float4* vr = (const float4*)(vs + j * kD + e0);
#pragma unroll
    for (int m = 0; m < 4; ++m) {
      float4 vv = vr[m];
      acc[4*m+0] += wk * vv.x;
      acc[4*m+1] += wk * vv.y;
      acc[4*m+2] += wk * vv.z;
      acc[4*m+3] += wk * vv.w;
    }
  }

  float4* Ab = (float4*)(A + (size_t)idx * (kD * kD) + d * kD + e0);
#pragma unroll
  for (int m = 0; m < 4; ++m)
    Ab[m] = make_float4(acc[4*m+0], acc[4*m+1], acc[4*m+2], acc[4*m+3]);
}

// ---------------------------------------------------------------------------
// Pass 2: in-place scan.  After: A[bh][c] = P_c (state BEFORE chunk c)
// P_0 = 0 ; P_{c+1} = gamma^C * P_c + A_c
// grid = B*H*4 blocks (each block owns a quarter of the 64x64 state),
// 256 threads, each thread scans one float4 -> short dependence chain.
// ---------------------------------------------------------------------------
__global__ __launch_bounds__(256) void ret_scan(float* __restrict__ A) {
  const int blk = blockIdx.x;
  const int bh = blk >> 2;
  const int quarter = blk & 3;
  const int h = bh % kH;
  const int t = threadIdx.x;
  const float log2g = log2f(1.0f - exp2f(-5.0f - (float)h));
  const float gC = exp2f((float)kC * log2g);

  float4 s = make_float4(0.f, 0.f, 0.f, 0.f);
  float4* base = (float4*)A + (size_t)bh * kNC * (kD * kD / 4)
               + quarter * 256 + t;
  for (int c = 0; c < kNC; ++c) {
    float4* p = base + c * (kD * kD / 4);
    float4 a = *p;
    *p = s;
    s.x = gC * s.x + a.x;
    s.y = gC * s.y + a.y;
    s.z = gC * s.z + a.z;
    s.w = gC * s.w + a.w;
  }
}

// ---------------------------------------------------------------------------
// Pass 3: out = scale * ( gamma^(ii+1) * q . P   +   causal-decayed QK^T V )
// grid = B*H*NC blocks, 256 threads: thread t -> row i = t>>2, e-slice (t&3)*16
// All operands read from LDS (no big per-thread arrays -> no scratch spills).
// qs/ks padded to stride 68 floats (17 float4) to break bank conflicts on the
// strided row reads in Phase A. P and the score buffer share one union (P is
// dead after Phase 0).
// ---------------------------------------------------------------------------
__global__ __launch_bounds__(256, 2) void ret_out(const float* __restrict__ Q,
                                                  const float* __restrict__ K,
                                                  const float* __restrict__ V,
                                                  const float* __restrict__ P,
                                                  float* __restrict__ O) {
  const int idx = blockIdx.x;
  const int h = (idx / kNC) % kH;
  const int t = threadIdx.x;

  __shared__ float qs[kC * 68];        // padded rows (17 float4)
  __shared__ float ks[kC * 68];        // padded rows
  __shared__ float vs[kC * kD];        // stride 64 (broadcast reads only)
  __shared__ float un[kC * 65];        // union: Ps (first 4096) then scores (stride 65)
  __shared__ float pt[kC + 1];

  const size_t gbase = (size_t)idx * (kC * kD);
  {
    const float4* gq = (const float4*)(Q + gbase);
    const float4* gk = (const float4*)(K + gbase);
    const float4* gv = (const float4*)(V + gbase);
    const float4* gp = (const float4*)(P + (size_t)idx * (kD * kD));
#pragma unroll
    for (int n0 = 0; n0 < 4; ++n0) {
      const int n = t + 256 * n0;
      const int row = n >> 4, c = n & 15;
      ((float4*)qs)[row * 17 + c] = gq[n];
      ((float4*)ks)[row * 17 + c] = gk[n];
      ((float4*)vs)[n] = gv[n];
      ((float4*)un)[n] = gp[n];
    }
  }
  const float log2g = log2f(1.0f - exp2f(-5.0f - (float)h));
  if (t <= kC) pt[t] = exp2f((float)t * log2g);
  __syncthreads();

  const int i = t >> 2;           // output row (wave holds 16 consecutive rows)
  const int e0 = (t & 3) * 16;    // output column slice

  float acc[16];
#pragma unroll
  for (int m = 0; m < 16; ++m) acc[m] = 0.0f;

  // Phase 0: inter-chunk  acc = q . P   (P in `un`)
  for (int d = 0; d < kD; ++d) {
    const float wq = qs[i * 68 + d];
    const float4* pr = (const float4*)(un + d * kD + e0);
#pragma unroll
    for (int m = 0; m < 4; ++m) {
      float4 pv = pr[m];
      acc[4*m+0] += wq * pv.x;
      acc[4*m+1] += wq * pv.y;
      acc[4*m+2] += wq * pv.z;
      acc[4*m+3] += wq * pv.w;
    }
  }
  {
    const float wI = pt[i + 1];
#pragma unroll
    for (int m = 0; m < 16; ++m) acc[m] *= wI;
  }

  __syncthreads();   // Phase 0 reads of `un` (P) complete before score writes

  // Phase A: causal decayed scores -> un (stride 65).
  // d4-outer / j-inner: only part[16] live; q read 16x, k 256x per thread.
  // j = (t&3) + 4*jn  => consecutive j within a wave: conflict-free k reads.
  {
    const int jb = t & 3;
    float part[16];
#pragma unroll
    for (int jn = 0; jn < 16; ++jn) part[jn] = 0.0f;
#pragma unroll
    for (int d4 = 0; d4 < 16; ++d4) {
      const float4 q4 = ((const float4*)qs)[i * 17 + d4];
#pragma unroll
      for (int jn = 0; jn < 16; ++jn) {
        const float4 k4 = ((const float4*)ks)[(jb + 4 * jn) * 17 + d4];
        part[jn] += q4.x * k4.x + q4.y * k4.y + q4.z * k4.z + q4.w * k4.w;
      }
    }
#pragma unroll
    for (int jn = 0; jn < 16; ++jn) {
      const int j = jb + 4 * jn;
      un[i * 65 + j] = (j <= i) ? part[jn] * pt[i - j] : 0.0f;
    }
  }
  __syncthreads();

  // Phase B: PV accumulate (wave-uniform bound; zeros above diagonal)
  {
    const int jmax = i | 15;     // uniform within a wave
    for (int j = 0; j <= jmax; ++j) {
      const float w = un[i * 65 + j];
      const float4* vr = (const float4*)(vs + j * kD + e0);
#pragma unroll
      for (int m = 0; m < 4; ++m) {
        float4 vv = vr[m];
        acc[4*m+0] += w * vv.x;
        acc[4*m+1] += w * vv.y;
        acc[4*m+2] += w * vv.z;
        acc[4*m+3] += w * vv.w;
      }
    }
  }

  float4* ob = (float4*)(O + gbase + i * kD + e0);
#pragma unroll
  for (int m = 0; m < 4; ++m)
    ob[m] = make_float4(kScale * acc[4*m+0], kScale * acc[4*m+1],
                        kScale * acc[4*m+2], kScale * acc[4*m+3]);
}

// ---------------------------------------------------------------------------
// Fallback (no workspace needed): one block per (b,h) walks all chunks with
// the state held in LDS.  Used only if ws_size is too small.
// ---------------------------------------------------------------------------
__global__ __launch_bounds__(256) void ret_fallback(const float* __restrict__ Q,
                                                    const float* __restrict__ K,
                                                    const float* __restrict__ V,
                                                    float* __restrict__ O) {
  const int bh = blockIdx.x;
  const int h = bh % kH;
  const int t = threadIdx.x;

  __shared__ float qs[kC * 68];
  __shared__ float ks[kC * 68];
  __shared__ float vs[kC * kD];
  __shared__ float St[kD * kD];
  __shared__ float ss[kC * 65];
  __shared__ float pt[kC + 1];

  const float log2g = log2f(1.0f - exp2f(-5.0f - (float)h));
  const float gC = exp2f((float)kC * log2g);
  if (t <= kC) pt[t] = exp2f((float)t * log2g);
#pragma unroll
  for (int n = 0; n < 4; ++n) ((float4*)St)[t + 256*n] = make_float4(0.f,0.f,0.f,0.f);
  __syncthreads();

  const int i = t >> 2;
  const int e0 = (t & 3) * 16;

  for (int c = 0; c < kNC; ++c) {
    const size_t gbase = ((size_t)bh * kS + (size_t)c * kC) * kD;
#pragma unroll
    for (int n0 = 0; n0 < 4; ++n0) {
      const int n = t + 256 * n0;
      const int row = n >> 4, cc = n & 15;
      ((float4*)qs)[row * 17 + cc] = ((const float4*)(Q + gbase))[n];
      ((float4*)ks)[row * 17 + cc] = ((const float4*)(K + gbase))[n];
      ((float4*)vs)[n] = ((const float4*)(V + gbase))[n];
    }
    __syncthreads();

    float acc[16];
#pragma unroll
    for (int m = 0; m < 16; ++m) acc[m] = 0.0f;
    for (int d = 0; d < kD; ++d) {
      const float wq = qs[i * 68 + d];
      const float4* pr = (const float4*)(St + d * kD + e0);
#pragma unroll
      for (int m = 0; m < 4; ++m) {
        float4 pv = pr[m];
        acc[4*m+0]+=wq*pv.x; acc[4*m+1]+=wq*pv.y; acc[4*m+2]+=wq*pv.z; acc[4*m+3]+=wq*pv.w;
      }
    }
    const float wI = pt[i + 1];
#pragma unroll
    for (int m = 0; m < 16; ++m) acc[m] *= wI;

    {
      const int jb = t & 3;
      float part[16];
#pragma unroll
      for (int jn = 0; jn < 16; ++jn) part[jn] = 0.0f;
#pragma unroll
      for (int d4 = 0; d4 < 16; ++d4) {
        const float4 q4 = ((const float4*)qs)[i * 17 + d4];
#pragma unroll
        for (int jn = 0; jn < 16; ++jn) {
          const float4 k4 = ((const float4*)ks)[(jb + 4 * jn) * 17 + d4];
          part[jn] += q4.x*k4.x + q4.y*k4.y + q4.z*k4.z + q4.w*k4.w;
        }
      }
#pragma unroll
      for (int jn = 0; jn < 16; ++jn) {
        const int j = jb + 4 * jn;
        ss[i * 65 + j] = (j <= i) ? part[jn] * pt[i - j] : 0.0f;
      }
    }
    __syncthreads();

    {
      const int jmax = i | 15;
      for (int j = 0; j <= jmax; ++j) {
        const float w = ss[i * 65 + j];
        const float4* vr = (const float4*)(vs + j * kD + e0);
#pragma unroll
        for (int m = 0; m < 4; ++m) {
          float4 vv = vr[m];
          acc[4*m+0]+=w*vv.x; acc[4*m+1]+=w*vv.y; acc[4*m+2]+=w*vv.z; acc[4*m+3]+=w*vv.w;
        }
      }
    }

    {
      float4* ob = (float4*)(O + gbase + (size_t)i * kD + e0);
#pragma unroll
      for (int m = 0; m < 4; ++m)
        ob[m] = make_float4(kScale*acc[4*m+0], kScale*acc[4*m+1],
                            kScale*acc[4*m+2], kScale*acc[4*m+3]);
    }

    // State update: St = gC*St + sum_j gamma^(C-1-j) k[j][d] v[j][e]
    {
      float upd[16];
#pragma unroll
      for (int m = 0; m < 16; ++m) upd[m] = 0.0f;
      for (int j = 0; j < kC; ++j) {
        const float wk = pt[kC - 1 - j] * ks[j * 68 + i];
        const float4* vr = (const float4*)(vs + j * kD + e0);
#pragma unroll
        for (int m = 0; m < 4; ++m) {
          float4 vv = vr[m];
          upd[4*m+0]+=wk*vv.x; upd[4*m+1]+=wk*vv.y; upd[4*m+2]+=wk*vv.z; upd[4*m+3]+=wk*vv.w;
        }
      }
      __syncthreads();
#pragma unroll
      for (int m = 0; m < 16; ++m)
        St[i * kD + e0 + m] = gC * St[i * kD + e0 + m] + upd[m];
      __syncthreads();
    }
  }
}

// ---------------------------------------------------------------------------
extern "C" void kernel_launch(void* const* d_in, const int* in_sizes, int n_in,
                              void* d_out, int out_size, void* d_ws, size_t ws_size,
                              hipStream_t stream) {
  const float* q = (const float*)d_in[0];
  const float* k = (const float*)d_in[1];
  const float* v = (const float*)d_in[2];
  float* out = (float*)d_out;

  const size_t need = (size_t)kB * kH * kNC * kD * kD * sizeof(float); // 16 MiB
  if (ws_size >= need) {
    float* A = (float*)d_ws;
    ret_partial<<<kB * kH * kNC, 256, 0, stream>>>(k, v, A);
    ret_scan<<<kB * kH * 4, 256, 0, stream>>>(A);
    ret_out<<<kB * kH * kNC, 256, 0, stream>>>(q, k, v, A, out);
  } else {
    ret_fallback<<<kB * kH, 256, 0, stream>>>(q, k, v, out);
  }
}

// Round 3
// 34.067 us; speedup vs baseline: 13.6725x; 13.6725x over previous
//
#include <hip/hip_runtime.h>
#include <math.h>

namespace {
constexpr int kB = 2, kH = 16, kS = 2048, kD = 64, kC = 64;
constexpr int kNC = kS / kC;          // 32 chunks
constexpr float kScale = 0.125f;      // 1/sqrt(64)
}

typedef _Float16 f16;
typedef f16 f16x8 __attribute__((ext_vector_type(8)));
typedef f16 f16x4 __attribute__((ext_vector_type(4)));
typedef float f32x4 __attribute__((ext_vector_type(4)));

// Swizzled index (f16 units) for a row-major [64][64] f16 LDS tile.
// Row stride = 128B -> all rows hit the same banks; XOR row bits into the
// 16B-slot index (byte bit4..6 == f16 bit3..5) to spread them (T2).
__device__ __forceinline__ int swz(int row, int col) {
  return row * 64 + (col ^ ((row & 7) << 3));
}

// ---------------------------------------------------------------------------
// Pass 1: AT_c[e][d] = sum_j gamma^(C-1-j) v[j][e] k[j][d]   (= A_c transposed)
// via MFMA:  AT = VT' * KT^T  with VT'[e][j] = decay*v, KT[d][j] = k^T.
// grid = B*H*NC blocks, 256 threads (4 waves; wave w owns e-block w).
// ---------------------------------------------------------------------------
__global__ __launch_bounds__(256) void ret_partial(const float* __restrict__ K,
                                                   const float* __restrict__ V,
                                                   float* __restrict__ A) {
  const int idx = blockIdx.x;               // (b*H + h)*NC + c
  const int h = (idx / kNC) % kH;
  const int t = threadIdx.x;

  __shared__ f16 kt[64 * 64];    // K^T  [d][j]
  __shared__ f16 vtd[64 * 64];   // decayed V^T  [e][j]

  const float log2g = log2f(1.0f - exp2f(-5.0f - (float)h));
  const size_t gbase = (size_t)idx * (kC * kD);

#pragma unroll
  for (int n0 = 0; n0 < 4; ++n0) {
    const int n = t + 256 * n0;
    const int j = n >> 4;            // source row
    const int c4 = n & 15;           // float4 column
    const float4 fk = ((const float4*)(K + gbase))[n];
    const float4 fv = ((const float4*)(V + gbase))[n];
    const float w = exp2f((float)(kC - 1 - j) * log2g);
    kt[swz(c4 * 4 + 0, j)] = (f16)fk.x;
    kt[swz(c4 * 4 + 1, j)] = (f16)fk.y;
    kt[swz(c4 * 4 + 2, j)] = (f16)fk.z;
    kt[swz(c4 * 4 + 3, j)] = (f16)fk.w;
    vtd[swz(c4 * 4 + 0, j)] = (f16)(fv.x * w);
    vtd[swz(c4 * 4 + 1, j)] = (f16)(fv.y * w);
    vtd[swz(c4 * 4 + 2, j)] = (f16)(fv.z * w);
    vtd[swz(c4 * 4 + 3, j)] = (f16)(fv.w * w);
  }
  __syncthreads();

  const int lane = t & 63;
  const int wv = t >> 6;           // wave id == te (e block)
  const int r16 = lane & 15;
  const int g = lane >> 4;

  const f16x8 aV0 = *(const f16x8*)&vtd[swz(wv * 16 + r16, g * 8)];
  const f16x8 aV1 = *(const f16x8*)&vtd[swz(wv * 16 + r16, 32 + g * 8)];

  float* Ab = A + (size_t)idx * (kD * kD);
#pragma unroll
  for (int td = 0; td < 4; ++td) {
    const f16x8 b0 = *(const f16x8*)&kt[swz(td * 16 + r16, g * 8)];
    const f16x8 b1 = *(const f16x8*)&kt[swz(td * 16 + r16, 32 + g * 8)];
    f32x4 c = {0.f, 0.f, 0.f, 0.f};
    c = __builtin_amdgcn_mfma_f32_16x16x32_f16(aV0, b0, c, 0, 0, 0);
    c = __builtin_amdgcn_mfma_f32_16x16x32_f16(aV1, b1, c, 0, 0, 0);
#pragma unroll
    for (int rr = 0; rr < 4; ++rr) {
      const int e = wv * 16 + g * 4 + rr;     // D row
      const int d = td * 16 + r16;            // D col
      Ab[e * kD + d] = c[rr];
    }
  }
}

// ---------------------------------------------------------------------------
// Pass 2: in-place scan (layout-agnostic elementwise on the 64x64 state).
// After: slot c holds PT_c (transposed state BEFORE chunk c), fp32.
// ---------------------------------------------------------------------------
__global__ __launch_bounds__(256) void ret_scan(float* __restrict__ A) {
  const int blk = blockIdx.x;
  const int bh = blk >> 2;
  const int quarter = blk & 3;
  const int h = bh % kH;
  const int t = threadIdx.x;
  const float log2g = log2f(1.0f - exp2f(-5.0f - (float)h));
  const float gC = exp2f((float)kC * log2g);

  float4 s = make_float4(0.f, 0.f, 0.f, 0.f);
  float4* base = (float4*)A + (size_t)bh * kNC * (kD * kD / 4)
               + quarter * 256 + t;
  for (int c = 0; c < kNC; ++c) {
    float4* p = base + c * (kD * kD / 4);
    float4 a = *p;
    *p = s;
    s.x = gC * s.x + a.x;
    s.y = gC * s.y + a.y;
    s.z = gC * s.z + a.z;
    s.w = gC * s.w + a.w;
  }
}

// ---------------------------------------------------------------------------
// Pass 3: O = scale * ( gamma^(ii+1) * Q.P  +  (QK^T .* decay_mask) V )
// All matmuls via mfma_f32_16x16x32_f16.  4 waves; wave w owns output
// row-block w (and S' row-block w -> no second barrier needed).
// ---------------------------------------------------------------------------
__global__ __launch_bounds__(256) void ret_out(const float* __restrict__ Q,
                                               const float* __restrict__ K,
                                               const float* __restrict__ V,
                                               const float* __restrict__ P,
                                               float* __restrict__ O) {
  const int idx = blockIdx.x;
  const int h = (idx / kNC) % kH;
  const int t = threadIdx.x;

  __shared__ f16 qs[64 * 64];    // Q  [i][d]
  __shared__ f16 ks[64 * 64];    // K  [j][d]
  __shared__ f16 vt[64 * 64];    // V^T [e][j]
  __shared__ f16 ptl[64 * 64];   // P^T [e][d]
  __shared__ f16 sp[64 * 64];    // S' [i][j] (decayed, masked, scaled)

  const float log2g = log2f(1.0f - exp2f(-5.0f - (float)h));
  const size_t gbase = (size_t)idx * (kC * kD);

#pragma unroll
  for (int n0 = 0; n0 < 4; ++n0) {
    const int n = t + 256 * n0;
    const int row = n >> 4;
    const int c4 = n & 15;
    const float4 fq = ((const float4*)(Q + gbase))[n];
    const float4 fk = ((const float4*)(K + gbase))[n];
    const float4 fv = ((const float4*)(V + gbase))[n];
    const float4 fp = ((const float4*)(P + (size_t)idx * (kD * kD)))[n];
    const f16x4 hq = {(f16)fq.x, (f16)fq.y, (f16)fq.z, (f16)fq.w};
    const f16x4 hk = {(f16)fk.x, (f16)fk.y, (f16)fk.z, (f16)fk.w};
    const f16x4 hp = {(f16)fp.x, (f16)fp.y, (f16)fp.z, (f16)fp.w};
    *(f16x4*)&qs[swz(row, c4 * 4)] = hq;
    *(f16x4*)&ks[swz(row, c4 * 4)] = hk;
    *(f16x4*)&ptl[swz(row, c4 * 4)] = hp;
    vt[swz(c4 * 4 + 0, row)] = (f16)fv.x;
    vt[swz(c4 * 4 + 1, row)] = (f16)fv.y;
    vt[swz(c4 * 4 + 2, row)] = (f16)fv.z;
    vt[swz(c4 * 4 + 3, row)] = (f16)fv.w;
  }
  __syncthreads();

  const int lane = t & 63;
  const int wv = t >> 6;           // wave id == ti (output row block)
  const int r16 = lane & 15;
  const int g = lane >> 4;

  // Q fragments for this wave's row block (reused by QK^T and Q.P)
  const f16x8 aQ0 = *(const f16x8*)&qs[swz(wv * 16 + r16, g * 8)];
  const f16x8 aQ1 = *(const f16x8*)&qs[swz(wv * 16 + r16, 32 + g * 8)];

  // ---- S' = scale * decay_mask .* (Q K^T) -> LDS f16 -------------------
#pragma unroll
  for (int tj = 0; tj < 4; ++tj) {
    const f16x8 b0 = *(const f16x8*)&ks[swz(tj * 16 + r16, g * 8)];
    const f16x8 b1 = *(const f16x8*)&ks[swz(tj * 16 + r16, 32 + g * 8)];
    f32x4 c = {0.f, 0.f, 0.f, 0.f};
    c = __builtin_amdgcn_mfma_f32_16x16x32_f16(aQ0, b0, c, 0, 0, 0);
    c = __builtin_amdgcn_mfma_f32_16x16x32_f16(aQ1, b1, c, 0, 0, 0);
#pragma unroll
    for (int rr = 0; rr < 4; ++rr) {
      const int i = wv * 16 + g * 4 + rr;   // D row -> query index
      const int j = tj * 16 + r16;          // D col -> key index
      const float w = (j <= i) ? kScale * exp2f((float)(i - j) * log2g) : 0.f;
      sp[swz(i, j)] = (f16)(c[rr] * w);
    }
  }

  // ---- inter-chunk: acc = scale * gamma^(ii+1) * (Q . P) ---------------
  float rowfac[4];
#pragma unroll
  for (int rr = 0; rr < 4; ++rr)
    rowfac[rr] = kScale * exp2f((float)(wv * 16 + g * 4 + rr + 1) * log2g);

  f32x4 acc[4];
#pragma unroll
  for (int te = 0; te < 4; ++te) {
    const f16x8 b0 = *(const f16x8*)&ptl[swz(te * 16 + r16, g * 8)];
    const f16x8 b1 = *(const f16x8*)&ptl[swz(te * 16 + r16, 32 + g * 8)];
    f32x4 c = {0.f, 0.f, 0.f, 0.f};
    c = __builtin_amdgcn_mfma_f32_16x16x32_f16(aQ0, b0, c, 0, 0, 0);
    c = __builtin_amdgcn_mfma_f32_16x16x32_f16(aQ1, b1, c, 0, 0, 0);
#pragma unroll
    for (int rr = 0; rr < 4; ++rr) c[rr] *= rowfac[rr];
    acc[te] = c;
  }

  // ---- intra-chunk PV: acc += S' V  (S' rows were written by THIS wave;
  //      within-wave LDS write->read needs no __syncthreads) -------------
  const f16x8 aS0 = *(const f16x8*)&sp[swz(wv * 16 + r16, g * 8)];
  const f16x8 aS1 = *(const f16x8*)&sp[swz(wv * 16 + r16, 32 + g * 8)];
#pragma unroll
  for (int te = 0; te < 4; ++te) {
    const f16x8 b0 = *(const f16x8*)&vt[swz(te * 16 + r16, g * 8)];
    const f16x8 b1 = *(const f16x8*)&vt[swz(te * 16 + r16, 32 + g * 8)];
    acc[te] = __builtin_amdgcn_mfma_f32_16x16x32_f16(aS0, b0, acc[te], 0, 0, 0);
    acc[te] = __builtin_amdgcn_mfma_f32_16x16x32_f16(aS1, b1, acc[te], 0, 0, 0);
  }

  // ---- store O[i][e] ----------------------------------------------------
  float* Ob = O + gbase;
#pragma unroll
  for (int te = 0; te < 4; ++te) {
#pragma unroll
    for (int rr = 0; rr < 4; ++rr) {
      const int i = wv * 16 + g * 4 + rr;
      const int e = te * 16 + r16;
      Ob[i * kD + e] = acc[te][rr];
    }
  }
}

// ---------------------------------------------------------------------------
// Fallback (no workspace): fp32 VALU, one block per (b,h).  Safety net only.
// ---------------------------------------------------------------------------
__global__ __launch_bounds__(256) void ret_fallback(const float* __restrict__ Q,
                                                    const float* __restrict__ K,
                                                    const float* __restrict__ V,
                                                    float* __restrict__ O) {
  const int bh = blockIdx.x;
  const int h = bh % kH;
  const int t = threadIdx.x;

  __shared__ float qs[kC * 68];
  __shared__ float ks[kC * 68];
  __shared__ float vs[kC * kD];
  __shared__ float St[kD * kD];
  __shared__ float ss[kC * 65];
  __shared__ float pt[kC + 1];

  const float log2g = log2f(1.0f - exp2f(-5.0f - (float)h));
  const float gC = exp2f((float)kC * log2g);
  if (t <= kC) pt[t] = exp2f((float)t * log2g);
#pragma unroll
  for (int n = 0; n < 4; ++n) ((float4*)St)[t + 256*n] = make_float4(0.f,0.f,0.f,0.f);
  __syncthreads();

  const int i = t >> 2;
  const int e0 = (t & 3) * 16;

  for (int c = 0; c < kNC; ++c) {
    const size_t gbase = ((size_t)bh * kS + (size_t)c * kC) * kD;
#pragma unroll
    for (int n0 = 0; n0 < 4; ++n0) {
      const int n = t + 256 * n0;
      const int row = n >> 4, cc = n & 15;
      ((float4*)qs)[row * 17 + cc] = ((const float4*)(Q + gbase))[n];
      ((float4*)ks)[row * 17 + cc] = ((const float4*)(K + gbase))[n];
      ((float4*)vs)[n] = ((const float4*)(V + gbase))[n];
    }
    __syncthreads();

    float acc[16];
#pragma unroll
    for (int m = 0; m < 16; ++m) acc[m] = 0.0f;
    for (int d = 0; d < kD; ++d) {
      const float wq = qs[i * 68 + d];
      const float4* pr = (const float4*)(St + d * kD + e0);
#pragma unroll
      for (int m = 0; m < 4; ++m) {
        float4 pv = pr[m];
        acc[4*m+0]+=wq*pv.x; acc[4*m+1]+=wq*pv.y; acc[4*m+2]+=wq*pv.z; acc[4*m+3]+=wq*pv.w;
      }
    }
    const float wI = pt[i + 1];
#pragma unroll
    for (int m = 0; m < 16; ++m) acc[m] *= wI;

    {
      const int jb = t & 3;
      float part[16];
#pragma unroll
      for (int jn = 0; jn < 16; ++jn) part[jn] = 0.0f;
#pragma unroll
      for (int d4 = 0; d4 < 16; ++d4) {
        const float4 q4 = ((const float4*)qs)[i * 17 + d4];
#pragma unroll
        for (int jn = 0; jn < 16; ++jn) {
          const float4 k4 = ((const float4*)ks)[(jb + 4 * jn) * 17 + d4];
          part[jn] += q4.x*k4.x + q4.y*k4.y + q4.z*k4.z + q4.w*k4.w;
        }
      }
#pragma unroll
      for (int jn = 0; jn < 16; ++jn) {
        const int j = jb + 4 * jn;
        ss[i * 65 + j] = (j <= i) ? part[jn] * pt[i - j] : 0.0f;
      }
    }
    __syncthreads();

    {
      const int jmax = i | 15;
      for (int j = 0; j <= jmax; ++j) {
        const float w = ss[i * 65 + j];
        const float4* vr = (const float4*)(vs + j * kD + e0);
#pragma unroll
        for (int m = 0; m < 4; ++m) {
          float4 vv = vr[m];
          acc[4*m+0]+=w*vv.x; acc[4*m+1]+=w*vv.y; acc[4*m+2]+=w*vv.z; acc[4*m+3]+=w*vv.w;
        }
      }
    }

    {
      float4* ob = (float4*)(O + gbase + (size_t)i * kD + e0);
#pragma unroll
      for (int m = 0; m < 4; ++m)
        ob[m] = make_float4(kScale*acc[4*m+0], kScale*acc[4*m+1],
                            kScale*acc[4*m+2], kScale*acc[4*m+3]);
    }

    {
      float upd[16];
#pragma unroll
      for (int m = 0; m < 16; ++m) upd[m] = 0.0f;
      for (int j = 0; j < kC; ++j) {
        const float wk = pt[kC - 1 - j] * ks[j * 68 + i];
        const float4* vr = (const float4*)(vs + j * kD + e0);
#pragma unroll
        for (int m = 0; m < 4; ++m) {
          float4 vv = vr[m];
          upd[4*m+0]+=wk*vv.x; upd[4*m+1]+=wk*vv.y; upd[4*m+2]+=wk*vv.z; upd[4*m+3]+=wk*vv.w;
        }
      }
      __syncthreads();
#pragma unroll
      for (int m = 0; m < 16; ++m)
        St[i * kD + e0 + m] = gC * St[i * kD + e0 + m] + upd[m];
      __syncthreads();
    }
  }
}

// ---------------------------------------------------------------------------
extern "C" void kernel_launch(void* const* d_in, const int* in_sizes, int n_in,
                              void* d_out, int out_size, void* d_ws, size_t ws_size,
                              hipStream_t stream) {
  const float* q = (const float*)d_in[0];
  const float* k = (const float*)d_in[1];
  const float* v = (const float*)d_in[2];
  float* out = (float*)d_out;

  const size_t need = (size_t)kB * kH * kNC * kD * kD * sizeof(float); // 16 MiB
  if (ws_size >= need) {
    float* A = (float*)d_ws;
    ret_partial<<<kB * kH * kNC, 256, 0, stream>>>(k, v, A);
    ret_scan<<<kB * kH * 4, 256, 0, stream>>>(A);
    ret_out<<<kB * kH * kNC, 256, 0, stream>>>(q, k, v, A, out);
  } else {
    ret_fallback<<<kB * kH, 256, 0, stream>>>(q, k, v, out);
  }
}

// Round 4
// 30.081 us; speedup vs baseline: 15.4845x; 1.1325x over previous
//
#include <hip/hip_runtime.h>
#include <math.h>

namespace {
constexpr int kB = 2, kH = 16, kS = 2048, kD = 64, kC = 64;
constexpr int kNC = kS / kC;          // 32 chunks
constexpr float kScale = 0.125f;      // 1/sqrt(64)
}

typedef _Float16 f16;
typedef f16 f16x8 __attribute__((ext_vector_type(8)));
typedef f16 f16x4 __attribute__((ext_vector_type(4)));
typedef f16 f16x2 __attribute__((ext_vector_type(2)));
typedef float f32x4 __attribute__((ext_vector_type(4)));

// Swizzled index (f16 units) for a row-major [64][64] f16 LDS tile.
// Row stride = 128B -> all rows hit the same banks; XOR row bits into the
// 16B-slot index (byte bit4..6 == f16 bit3..5) to spread them (T2).
__device__ __forceinline__ int swz(int row, int col) {
  return row * 64 + (col ^ ((row & 7) << 3));
}

// ---------------------------------------------------------------------------
// Pass 1: AT_c[e][d] = sum_j gamma^(C-1-j) v[j][e] k[j][d]   (= A_c transposed)
// via MFMA:  AT = VT' * KT^T  with VT'[e][j] = decay*v, KT[d][j] = k^T.
// Output stored as f16 (workspace traffic halved; P is consumed as f16 anyway)
// grid = B*H*NC blocks, 256 threads (4 waves; wave w owns e-block w).
// ---------------------------------------------------------------------------
__global__ __launch_bounds__(256) void ret_partial(const float* __restrict__ K,
                                                   const float* __restrict__ V,
                                                   f16* __restrict__ A) {
  const int idx = blockIdx.x;               // (b*H + h)*NC + c
  const int h = (idx / kNC) % kH;
  const int t = threadIdx.x;

  __shared__ f16 kt[64 * 64];    // K^T  [d][j]
  __shared__ f16 vtd[64 * 64];   // decayed V^T  [e][j]

  const float log2g = log2f(1.0f - exp2f(-5.0f - (float)h));
  const size_t gbase = (size_t)idx * (kC * kD);

#pragma unroll
  for (int n0 = 0; n0 < 4; ++n0) {
    const int n = t + 256 * n0;
    const int j = n >> 4;            // source row
    const int c4 = n & 15;           // float4 column
    const float4 fk = ((const float4*)(K + gbase))[n];
    const float4 fv = ((const float4*)(V + gbase))[n];
    const float w = exp2f((float)(kC - 1 - j) * log2g);
    kt[swz(c4 * 4 + 0, j)] = (f16)fk.x;
    kt[swz(c4 * 4 + 1, j)] = (f16)fk.y;
    kt[swz(c4 * 4 + 2, j)] = (f16)fk.z;
    kt[swz(c4 * 4 + 3, j)] = (f16)fk.w;
    vtd[swz(c4 * 4 + 0, j)] = (f16)(fv.x * w);
    vtd[swz(c4 * 4 + 1, j)] = (f16)(fv.y * w);
    vtd[swz(c4 * 4 + 2, j)] = (f16)(fv.z * w);
    vtd[swz(c4 * 4 + 3, j)] = (f16)(fv.w * w);
  }
  __syncthreads();

  const int lane = t & 63;
  const int wv = t >> 6;           // wave id == te (e block)
  const int r16 = lane & 15;
  const int g = lane >> 4;

  const f16x8 aV0 = *(const f16x8*)&vtd[swz(wv * 16 + r16, g * 8)];
  const f16x8 aV1 = *(const f16x8*)&vtd[swz(wv * 16 + r16, 32 + g * 8)];

  f16* Ab = A + (size_t)idx * (kD * kD);
#pragma unroll
  for (int td = 0; td < 4; ++td) {
    const f16x8 b0 = *(const f16x8*)&kt[swz(td * 16 + r16, g * 8)];
    const f16x8 b1 = *(const f16x8*)&kt[swz(td * 16 + r16, 32 + g * 8)];
    f32x4 c = {0.f, 0.f, 0.f, 0.f};
    c = __builtin_amdgcn_mfma_f32_16x16x32_f16(aV0, b0, c, 0, 0, 0);
    c = __builtin_amdgcn_mfma_f32_16x16x32_f16(aV1, b1, c, 0, 0, 0);
#pragma unroll
    for (int rr = 0; rr < 4; ++rr) {
      const int e = wv * 16 + g * 4 + rr;     // D row
      const int d = td * 16 + r16;            // D col
      Ab[e * kD + d] = (f16)c[rr];
    }
  }
}

// ---------------------------------------------------------------------------
// Pass 2: in-place scan over f16 chunk states (fp32 accumulation in regs).
// After: slot c holds PT_c (transposed state BEFORE chunk c).
// grid = B*H*8 blocks, 256 threads; each thread owns one f16x2 (4B) lane.
// ---------------------------------------------------------------------------
__global__ __launch_bounds__(256) void ret_scan(f16* __restrict__ A) {
  const int blk = blockIdx.x;
  const int bh = blk >> 3;
  const int part = blk & 7;
  const int h = bh % kH;
  const int t = threadIdx.x;
  const float log2g = log2f(1.0f - exp2f(-5.0f - (float)h));
  const float gC = exp2f((float)kC * log2g);

  float sx = 0.f, sy = 0.f;
  f16x2* base = (f16x2*)A + (size_t)bh * kNC * 2048 + part * 256 + t;
  for (int c = 0; c < kNC; ++c) {
    f16x2* p = base + c * 2048;
    const f16x2 a = *p;
    const f16x2 sv = {(f16)sx, (f16)sy};
    *p = sv;
    sx = gC * sx + (float)a.x;
    sy = gC * sy + (float)a.y;
  }
}

// ---------------------------------------------------------------------------
// Pass 3: O = scale * ( gamma^(ii+1) * Q.P  +  (QK^T .* decay_mask) V )
// All matmuls via mfma_f32_16x16x32_f16.  4 waves; wave w owns output
// row-block w (and S' row-block w -> no second barrier needed).
// ---------------------------------------------------------------------------
__global__ __launch_bounds__(256) void ret_out(const float* __restrict__ Q,
                                               const float* __restrict__ K,
                                               const float* __restrict__ V,
                                               const f16* __restrict__ P,
                                               float* __restrict__ O) {
  const int idx = blockIdx.x;
  const int h = (idx / kNC) % kH;
  const int t = threadIdx.x;

  __shared__ f16 qs[64 * 64];    // Q  [i][d]
  __shared__ f16 ks[64 * 64];    // K  [j][d]
  __shared__ f16 vt[64 * 64];    // V^T [e][j]
  __shared__ f16 ptl[64 * 64];   // P^T [e][d]
  __shared__ f16 sp[64 * 64];    // S' [i][j] (decayed, masked, scaled)

  const float log2g = log2f(1.0f - exp2f(-5.0f - (float)h));
  const size_t gbase = (size_t)idx * (kC * kD);

#pragma unroll
  for (int n0 = 0; n0 < 4; ++n0) {
    const int n = t + 256 * n0;
    const int row = n >> 4;
    const int c4 = n & 15;
    const float4 fq = ((const float4*)(Q + gbase))[n];
    const float4 fk = ((const float4*)(K + gbase))[n];
    const float4 fv = ((const float4*)(V + gbase))[n];
    const f16x4 hq = {(f16)fq.x, (f16)fq.y, (f16)fq.z, (f16)fq.w};
    const f16x4 hk = {(f16)fk.x, (f16)fk.y, (f16)fk.z, (f16)fk.w};
    *(f16x4*)&qs[swz(row, c4 * 4)] = hq;
    *(f16x4*)&ks[swz(row, c4 * 4)] = hk;
    vt[swz(c4 * 4 + 0, row)] = (f16)fv.x;
    vt[swz(c4 * 4 + 1, row)] = (f16)fv.y;
    vt[swz(c4 * 4 + 2, row)] = (f16)fv.z;
    vt[swz(c4 * 4 + 3, row)] = (f16)fv.w;
  }
  // P tile is already f16 in workspace: straight vector copy (with swizzle)
  {
    const f16x8* gp = (const f16x8*)(P + (size_t)idx * (kD * kD));
#pragma unroll
    for (int n0 = 0; n0 < 2; ++n0) {
      const int n = t + 256 * n0;      // f16x8 index, 0..511
      const int row = n >> 3;
      const int c8 = (n & 7) * 8;
      *(f16x8*)&ptl[swz(row, c8)] = gp[n];
    }
  }
  __syncthreads();

  const int lane = t & 63;
  const int wv = t >> 6;           // wave id == ti (output row block)
  const int r16 = lane & 15;
  const int g = lane >> 4;

  // Q fragments for this wave's row block (reused by QK^T and Q.P)
  const f16x8 aQ0 = *(const f16x8*)&qs[swz(wv * 16 + r16, g * 8)];
  const f16x8 aQ1 = *(const f16x8*)&qs[swz(wv * 16 + r16, 32 + g * 8)];

  // ---- S' = scale * decay_mask .* (Q K^T) -> LDS f16 -------------------
#pragma unroll
  for (int tj = 0; tj < 4; ++tj) {
    const f16x8 b0 = *(const f16x8*)&ks[swz(tj * 16 + r16, g * 8)];
    const f16x8 b1 = *(const f16x8*)&ks[swz(tj * 16 + r16, 32 + g * 8)];
    f32x4 c = {0.f, 0.f, 0.f, 0.f};
    c = __builtin_amdgcn_mfma_f32_16x16x32_f16(aQ0, b0, c, 0, 0, 0);
    c = __builtin_amdgcn_mfma_f32_16x16x32_f16(aQ1, b1, c, 0, 0, 0);
#pragma unroll
    for (int rr = 0; rr < 4; ++rr) {
      const int i = wv * 16 + g * 4 + rr;   // D row -> query index
      const int j = tj * 16 + r16;          // D col -> key index
      const float w = (j <= i) ? kScale * exp2f((float)(i - j) * log2g) : 0.f;
      sp[swz(i, j)] = (f16)(c[rr] * w);
    }
  }

  // ---- inter-chunk: acc = scale * gamma^(ii+1) * (Q . P) ---------------
  float rowfac[4];
#pragma unroll
  for (int rr = 0; rr < 4; ++rr)
    rowfac[rr] = kScale * exp2f((float)(wv * 16 + g * 4 + rr + 1) * log2g);

  f32x4 acc[4];
#pragma unroll
  for (int te = 0; te < 4; ++te) {
    const f16x8 b0 = *(const f16x8*)&ptl[swz(te * 16 + r16, g * 8)];
    const f16x8 b1 = *(const f16x8*)&ptl[swz(te * 16 + r16, 32 + g * 8)];
    f32x4 c = {0.f, 0.f, 0.f, 0.f};
    c = __builtin_amdgcn_mfma_f32_16x16x32_f16(aQ0, b0, c, 0, 0, 0);
    c = __builtin_amdgcn_mfma_f32_16x16x32_f16(aQ1, b1, c, 0, 0, 0);
#pragma unroll
    for (int rr = 0; rr < 4; ++rr) c[rr] *= rowfac[rr];
    acc[te] = c;
  }

  // ---- intra-chunk PV: acc += S' V  (S' rows were written by THIS wave;
  //      within-wave LDS write->read needs no __syncthreads) -------------
  const f16x8 aS0 = *(const f16x8*)&sp[swz(wv * 16 + r16, g * 8)];
  const f16x8 aS1 = *(const f16x8*)&sp[swz(wv * 16 + r16, 32 + g * 8)];
#pragma unroll
  for (int te = 0; te < 4; ++te) {
    const f16x8 b0 = *(const f16x8*)&vt[swz(te * 16 + r16, g * 8)];
    const f16x8 b1 = *(const f16x8*)&vt[swz(te * 16 + r16, 32 + g * 8)];
    acc[te] = __builtin_amdgcn_mfma_f32_16x16x32_f16(aS0, b0, acc[te], 0, 0, 0);
    acc[te] = __builtin_amdgcn_mfma_f32_16x16x32_f16(aS1, b1, acc[te], 0, 0, 0);
  }

  // ---- store O[i][e] ----------------------------------------------------
  float* Ob = O + gbase;
#pragma unroll
  for (int te = 0; te < 4; ++te) {
#pragma unroll
    for (int rr = 0; rr < 4; ++rr) {
      const int i = wv * 16 + g * 4 + rr;
      const int e = te * 16 + r16;
      Ob[i * kD + e] = acc[te][rr];
    }
  }
}

// ---------------------------------------------------------------------------
// Fallback (no workspace): fp32 VALU, one block per (b,h).  Safety net only.
// ---------------------------------------------------------------------------
__global__ __launch_bounds__(256) void ret_fallback(const float* __restrict__ Q,
                                                    const float* __restrict__ K,
                                                    const float* __restrict__ V,
                                                    float* __restrict__ O) {
  const int bh = blockIdx.x;
  const int h = bh % kH;
  const int t = threadIdx.x;

  __shared__ float qs[kC * 68];
  __shared__ float ks[kC * 68];
  __shared__ float vs[kC * kD];
  __shared__ float St[kD * kD];
  __shared__ float ss[kC * 65];
  __shared__ float pt[kC + 1];

  const float log2g = log2f(1.0f - exp2f(-5.0f - (float)h));
  const float gC = exp2f((float)kC * log2g);
  if (t <= kC) pt[t] = exp2f((float)t * log2g);
#pragma unroll
  for (int n = 0; n < 4; ++n) ((float4*)St)[t + 256*n] = make_float4(0.f,0.f,0.f,0.f);
  __syncthreads();

  const int i = t >> 2;
  const int e0 = (t & 3) * 16;

  for (int c = 0; c < kNC; ++c) {
    const size_t gbase = ((size_t)bh * kS + (size_t)c * kC) * kD;
#pragma unroll
    for (int n0 = 0; n0 < 4; ++n0) {
      const int n = t + 256 * n0;
      const int row = n >> 4, cc = n & 15;
      ((float4*)qs)[row * 17 + cc] = ((const float4*)(Q + gbase))[n];
      ((float4*)ks)[row * 17 + cc] = ((const float4*)(K + gbase))[n];
      ((float4*)vs)[n] = ((const float4*)(V + gbase))[n];
    }
    __syncthreads();

    float acc[16];
#pragma unroll
    for (int m = 0; m < 16; ++m) acc[m] = 0.0f;
    for (int d = 0; d < kD; ++d) {
      const float wq = qs[i * 68 + d];
      const float4* pr = (const float4*)(St + d * kD + e0);
#pragma unroll
      for (int m = 0; m < 4; ++m) {
        float4 pv = pr[m];
        acc[4*m+0]+=wq*pv.x; acc[4*m+1]+=wq*pv.y; acc[4*m+2]+=wq*pv.z; acc[4*m+3]+=wq*pv.w;
      }
    }
    const float wI = pt[i + 1];
#pragma unroll
    for (int m = 0; m < 16; ++m) acc[m] *= wI;

    {
      const int jb = t & 3;
      float part[16];
#pragma unroll
      for (int jn = 0; jn < 16; ++jn) part[jn] = 0.0f;
#pragma unroll
      for (int d4 = 0; d4 < 16; ++d4) {
        const float4 q4 = ((const float4*)qs)[i * 17 + d4];
#pragma unroll
        for (int jn = 0; jn < 16; ++jn) {
          const float4 k4 = ((const float4*)ks)[(jb + 4 * jn) * 17 + d4];
          part[jn] += q4.x*k4.x + q4.y*k4.y + q4.z*k4.z + q4.w*k4.w;
        }
      }
#pragma unroll
      for (int jn = 0; jn < 16; ++jn) {
        const int j = jb + 4 * jn;
        ss[i * 65 + j] = (j <= i) ? part[jn] * pt[i - j] : 0.0f;
      }
    }
    __syncthreads();

    {
      const int jmax = i | 15;
      for (int j = 0; j <= jmax; ++j) {
        const float w = ss[i * 65 + j];
        const float4* vr = (const float4*)(vs + j * kD + e0);
#pragma unroll
        for (int m = 0; m < 4; ++m) {
          float4 vv = vr[m];
          acc[4*m+0]+=w*vv.x; acc[4*m+1]+=w*vv.y; acc[4*m+2]+=w*vv.z; acc[4*m+3]+=w*vv.w;
        }
      }
    }

    {
      float4* ob = (float4*)(O + gbase + (size_t)i * kD + e0);
#pragma unroll
      for (int m = 0; m < 4; ++m)
        ob[m] = make_float4(kScale*acc[4*m+0], kScale*acc[4*m+1],
                            kScale*acc[4*m+2], kScale*acc[4*m+3]);
    }

    {
      float upd[16];
#pragma unroll
      for (int m = 0; m < 16; ++m) upd[m] = 0.0f;
      for (int j = 0; j < kC; ++j) {
        const float wk = pt[kC - 1 - j] * ks[j * 68 + i];
        const float4* vr = (const float4*)(vs + j * kD + e0);
#pragma unroll
        for (int m = 0; m < 4; ++m) {
          float4 vv = vr[m];
          upd[4*m+0]+=wk*vv.x; upd[4*m+1]+=wk*vv.y; upd[4*m+2]+=wk*vv.z; upd[4*m+3]+=wk*vv.w;
        }
      }
      __syncthreads();
#pragma unroll
      for (int m = 0; m < 16; ++m)
        St[i * kD + e0 + m] = gC * St[i * kD + e0 + m] + upd[m];
      __syncthreads();
    }
  }
}

// ---------------------------------------------------------------------------
extern "C" void kernel_launch(void* const* d_in, const int* in_sizes, int n_in,
                              void* d_out, int out_size, void* d_ws, size_t ws_size,
                              hipStream_t stream) {
  const float* q = (const float*)d_in[0];
  const float* k = (const float*)d_in[1];
  const float* v = (const float*)d_in[2];
  float* out = (float*)d_out;

  const size_t need = (size_t)kB * kH * kNC * kD * kD * sizeof(f16); // 8.4 MiB
  if (ws_size >= need) {
    f16* A = (f16*)d_ws;
    ret_partial<<<kB * kH * kNC, 256, 0, stream>>>(k, v, A);
    ret_scan<<<kB * kH * 8, 256, 0, stream>>>(A);
    ret_out<<<kB * kH * kNC, 256, 0, stream>>>(q, k, v, A, out);
  } else {
    ret_fallback<<<kB * kH, 256, 0, stream>>>(q, k, v, out);
  }
}